// Round 7
// baseline (3516.008 us; speedup 1.0000x reference)
//
#include <hip/hip_runtime.h>
#include <hip/hip_fp16.h>

#define N_NODES 500000
#define N_EDGES 16000000
#define NB 1954          // ceil(N_NODES/256)
#define NPB_LOG 9
#define NPB 512          // nodes per bucket
#define NBUCK 977        // ceil(N_NODES/NPB)
#define NBUCK_PAD 1024
#define CH 32768         // edges per bucket_scatter block
#define NSB 489          // ceil(N_EDGES/CH)
#define TILE_LOG 15      // src tile = src>>15 -> 16 tiles of 32768 nodes

// ---------- fp16 pack/unpack helpers (fp32 math everywhere else) ----------
__device__ __forceinline__ float2 up2(int p) {
    __half2 h = *reinterpret_cast<__half2*>(&p);
    return __half22float2(h);
}
__device__ __forceinline__ int pk2(float a, float b) {
    __half2 h = __floats2half2_rn(a, b);
    return *reinterpret_cast<int*>(&h);
}

// ============================================================================
// Bucket sort by dst>>9 (LDS atomics), then per-bucket sort by src-tile
// ============================================================================

__global__ void bucket_hist(const int* __restrict__ dst, int* __restrict__ ghist) {
    __shared__ int lhist[NBUCK_PAD];
    for (int t = threadIdx.x; t < NBUCK_PAD; t += 256) lhist[t] = 0;
    __syncthreads();
    int stride = gridDim.x * 256;
    for (int i = blockIdx.x * 256 + threadIdx.x; i < N_EDGES; i += stride) {
        atomicAdd(&lhist[dst[i] >> NPB_LOG], 1);
    }
    __syncthreads();
    for (int t = threadIdx.x; t < NBUCK_PAD; t += 256) {
        int c = lhist[t];
        if (c) atomicAdd(&ghist[t], c);
    }
}

__global__ void bucket_scan(int* __restrict__ gcur, int* __restrict__ bbase) {
    __shared__ int s[256];
    int t = threadIdx.x;
    int v[4], sum = 0, loc[4];
#pragma unroll
    for (int j = 0; j < 4; ++j) {
        v[j] = gcur[t * 4 + j];
        loc[j] = sum;
        sum += v[j];
    }
    s[t] = sum;
    __syncthreads();
    for (int o = 1; o < 256; o <<= 1) {
        int x = (t >= o) ? s[t - o] : 0;
        __syncthreads();
        s[t] += x;
        __syncthreads();
    }
    int excl = s[t] - sum;
#pragma unroll
    for (int j = 0; j < 4; ++j) {
        int e = excl + loc[j];
        bbase[t * 4 + j] = e;
        gcur[t * 4 + j] = e;
    }
    if (t == 255) bbase[NBUCK_PAD] = s[255];
}

__global__ void bucket_scatter(const int* __restrict__ src, const int* __restrict__ dst,
                               int* __restrict__ gcur, int* __restrict__ P) {
    __shared__ int lhist[NBUCK_PAD];
    __shared__ int lcur[NBUCK_PAD];
    for (int t = threadIdx.x; t < NBUCK_PAD; t += 256) lhist[t] = 0;
    __syncthreads();
    int e0 = blockIdx.x * CH;
    int e1 = min(e0 + CH, N_EDGES);
    for (int i = e0 + threadIdx.x; i < e1; i += 256) {
        atomicAdd(&lhist[dst[i] >> NPB_LOG], 1);
    }
    __syncthreads();
    for (int t = threadIdx.x; t < NBUCK_PAD; t += 256) {
        int c = lhist[t];
        lcur[t] = c ? atomicAdd(&gcur[t], c) : 0;
    }
    __syncthreads();
    for (int i = e0 + threadIdx.x; i < e1; i += 256) {
        int d = dst[i];
        int s = src[i];
        int b = d >> NPB_LOG;
        int pos = atomicAdd(&lcur[b], 1);
        P[pos] = ((d & (NPB - 1)) << 19) | s;
    }
}

// per-bucket counting sort of edges by src-tile (16 bins)
__global__ void tile_sort(const int* __restrict__ P, const int* __restrict__ bbase,
                          int* __restrict__ P2) {
    __shared__ int h16[16];
    __shared__ int c16[16];
    int t = threadIdx.x, b = blockIdx.x;
    int bb = bbase[b], be = bbase[b + 1];
    if (t < 16) h16[t] = 0;
    __syncthreads();
    for (int j = bb + t; j < be; j += 256) {
        atomicAdd(&h16[(P[j] & 0x7FFFF) >> TILE_LOG], 1);
    }
    __syncthreads();
    if (t == 0) {
        int s = 0;
#pragma unroll
        for (int i = 0; i < 16; ++i) {
            c16[i] = s;
            s += h16[i];
        }
    }
    __syncthreads();
    for (int j = bb + t; j < be; j += 256) {
        int p = P[j];
        int pos = atomicAdd(&c16[(p & 0x7FFFF) >> TILE_LOG], 1);
        P2[bb + pos] = p;
    }
}

// ============================================================================
// fp16 table prep
// ============================================================================

__global__ void convert_x(const float* __restrict__ x, int2* __restrict__ xh) {
    int i = blockIdx.x * 256 + threadIdx.x;
    if (i >= N_NODES) return;
    float4 v = ((const float4*)x)[i];
    int2 r;
    r.x = pk2(v.x, v.y);
    r.y = pk2(v.z, v.w);
    xh[i] = r;
}

// ============================================================================
// Cache-blocked aggregation layers: one block per 512-dst bucket,
// LDS fp32 accumulators, edges streamed in src-tile order.
// ============================================================================

// Layer 1: gather xh (8 B rows), self from fp32 x, out h1 fp16 (32 B stride)
__global__ void agg_l1(const int* __restrict__ P2, const int* __restrict__ bbase,
                       const int2* __restrict__ xh, const float* __restrict__ x,
                       const float* __restrict__ wl, const float* __restrict__ bl,
                       const float* __restrict__ wr, int* __restrict__ h1) {
    __shared__ float lacc[NPB * 5];   // stride 5, coprime to 32 banks
    __shared__ int ldeg[NPB];
    __shared__ float s_wl[40], s_wr[40], s_b[10];
    int t = threadIdx.x, b = blockIdx.x;
    for (int k = t; k < NPB * 5; k += 256) lacc[k] = 0.f;
    ldeg[t] = 0;
    ldeg[t + 256] = 0;
    if (t < 40) {
        s_wl[t] = wl[t];
        s_wr[t] = wr[t];
    }
    if (t >= 64 && t < 74) s_b[t - 64] = bl[t - 64];
    __syncthreads();

    int bb = bbase[b], be = bbase[b + 1];
    int j = bb + t;
    for (; j + 768 < be; j += 1024) {
        int p[4];
        p[0] = P2[j]; p[1] = P2[j + 256]; p[2] = P2[j + 512]; p[3] = P2[j + 768];
        int2 v[4];
#pragma unroll
        for (int u = 0; u < 4; ++u) v[u] = xh[p[u] & 0x7FFFF];
#pragma unroll
        for (int u = 0; u < 4; ++u) {
            int dl = p[u] >> 19;
            float2 f0 = up2(v[u].x), f1 = up2(v[u].y);
            float* a = &lacc[dl * 5];
            atomicAdd(a + 0, f0.x); atomicAdd(a + 1, f0.y);
            atomicAdd(a + 2, f1.x); atomicAdd(a + 3, f1.y);
            atomicAdd(&ldeg[dl], 1);
        }
    }
    for (; j < be; j += 256) {
        int p = P2[j];
        int dl = p >> 19;
        int2 v = xh[p & 0x7FFFF];
        float2 f0 = up2(v.x), f1 = up2(v.y);
        float* a = &lacc[dl * 5];
        atomicAdd(a + 0, f0.x); atomicAdd(a + 1, f0.y);
        atomicAdd(a + 2, f1.x); atomicAdd(a + 3, f1.y);
        atomicAdd(&ldeg[dl], 1);
    }
    __syncthreads();

    int node0 = b << NPB_LOG;
#pragma unroll
    for (int h = 0; h < 2; ++h) {
        int dl = t + h * 256;
        int node = node0 + dl;
        if (node >= N_NODES) continue;
        float inv = 1.f / fmaxf((float)ldeg[dl], 1.f);
        float a[4];
#pragma unroll
        for (int q = 0; q < 4; ++q) a[q] = lacc[dl * 5 + q] * inv;
        float4 xs = ((const float4*)x)[node];
        float xv[4] = {xs.x, xs.y, xs.z, xs.w};
        float r[10];
#pragma unroll
        for (int jj = 0; jj < 10; ++jj) {
            float s = s_b[jj];
#pragma unroll
            for (int kk = 0; kk < 4; ++kk) {
                s += s_wl[jj * 4 + kk] * a[kk] + s_wr[jj * 4 + kk] * xv[kk];
            }
            r[jj] = fmaxf(s, 0.f);
        }
        int4 o0;
        o0.x = pk2(r[0], r[1]); o0.y = pk2(r[2], r[3]);
        o0.z = pk2(r[4], r[5]); o0.w = pk2(r[6], r[7]);
        *(int4*)(h1 + (long)node * 8) = o0;
        h1[(long)node * 8 + 4] = pk2(r[8], r[9]);
    }
}

// Layer 2: gather h1 (20 B in 32 B stride), out h2 fp16 (40 B in 64 B stride)
__global__ void agg_l2(const int* __restrict__ P2, const int* __restrict__ bbase,
                       const int* __restrict__ h1,
                       const float* __restrict__ wl, const float* __restrict__ bl,
                       const float* __restrict__ wr, int* __restrict__ h2) {
    __shared__ float lacc[NPB * 11];  // stride 11, coprime to 32
    __shared__ int ldeg[NPB];
    __shared__ float s_wl[200], s_wr[200], s_b[20];
    int t = threadIdx.x, b = blockIdx.x;
    for (int k = t; k < NPB * 11; k += 256) lacc[k] = 0.f;
    ldeg[t] = 0;
    ldeg[t + 256] = 0;
    if (t < 200) {
        s_wl[t] = wl[t];
        s_wr[t] = wr[t];
    }
    if (t >= 224 && t < 244) s_b[t - 224] = bl[t - 224];
    __syncthreads();

    int bb = bbase[b], be = bbase[b + 1];
    int j = bb + t;
    for (; j + 768 < be; j += 1024) {
        int p[4];
        p[0] = P2[j]; p[1] = P2[j + 256]; p[2] = P2[j + 512]; p[3] = P2[j + 768];
        int4 va[4];
        int vb[4];
#pragma unroll
        for (int u = 0; u < 4; ++u) {
            const int* row = h1 + (long)(p[u] & 0x7FFFF) * 8;
            va[u] = *(const int4*)row;
            vb[u] = row[4];
        }
#pragma unroll
        for (int u = 0; u < 4; ++u) {
            int dl = p[u] >> 19;
            float* a = &lacc[dl * 11];
            float2 f0 = up2(va[u].x), f1 = up2(va[u].y), f2 = up2(va[u].z), f3 = up2(va[u].w), f4 = up2(vb[u]);
            atomicAdd(a + 0, f0.x); atomicAdd(a + 1, f0.y);
            atomicAdd(a + 2, f1.x); atomicAdd(a + 3, f1.y);
            atomicAdd(a + 4, f2.x); atomicAdd(a + 5, f2.y);
            atomicAdd(a + 6, f3.x); atomicAdd(a + 7, f3.y);
            atomicAdd(a + 8, f4.x); atomicAdd(a + 9, f4.y);
            atomicAdd(&ldeg[dl], 1);
        }
    }
    for (; j < be; j += 256) {
        int p = P2[j];
        int dl = p >> 19;
        const int* row = h1 + (long)(p & 0x7FFFF) * 8;
        int4 va = *(const int4*)row;
        int vb = row[4];
        float* a = &lacc[dl * 11];
        float2 f0 = up2(va.x), f1 = up2(va.y), f2 = up2(va.z), f3 = up2(va.w), f4 = up2(vb);
        atomicAdd(a + 0, f0.x); atomicAdd(a + 1, f0.y);
        atomicAdd(a + 2, f1.x); atomicAdd(a + 3, f1.y);
        atomicAdd(a + 4, f2.x); atomicAdd(a + 5, f2.y);
        atomicAdd(a + 6, f3.x); atomicAdd(a + 7, f3.y);
        atomicAdd(a + 8, f4.x); atomicAdd(a + 9, f4.y);
        atomicAdd(&ldeg[dl], 1);
    }
    __syncthreads();

    int node0 = b << NPB_LOG;
#pragma unroll
    for (int h = 0; h < 2; ++h) {
        int dl = t + h * 256;
        int node = node0 + dl;
        if (node >= N_NODES) continue;
        float inv = 1.f / fmaxf((float)ldeg[dl], 1.f);
        float a[10];
#pragma unroll
        for (int q = 0; q < 10; ++q) a[q] = lacc[dl * 11 + q] * inv;
        float xv[10];
        {
            const int* row = h1 + (long)node * 8;
            int4 va = *(const int4*)row;
            int vb = row[4];
            float2 f0 = up2(va.x), f1 = up2(va.y), f2 = up2(va.z), f3 = up2(va.w), f4 = up2(vb);
            xv[0] = f0.x; xv[1] = f0.y; xv[2] = f1.x; xv[3] = f1.y;
            xv[4] = f2.x; xv[5] = f2.y; xv[6] = f3.x; xv[7] = f3.y;
            xv[8] = f4.x; xv[9] = f4.y;
        }
        float r[20];
#pragma unroll
        for (int jj = 0; jj < 20; ++jj) {
            float s = s_b[jj];
#pragma unroll
            for (int kk = 0; kk < 10; ++kk) {
                s += s_wl[jj * 10 + kk] * a[kk] + s_wr[jj * 10 + kk] * xv[kk];
            }
            r[jj] = fmaxf(s, 0.f);
        }
        int* o = h2 + (long)node * 16;
        int4 o0, o1;
        o0.x = pk2(r[0], r[1]);   o0.y = pk2(r[2], r[3]);
        o0.z = pk2(r[4], r[5]);   o0.w = pk2(r[6], r[7]);
        o1.x = pk2(r[8], r[9]);   o1.y = pk2(r[10], r[11]);
        o1.z = pk2(r[12], r[13]); o1.w = pk2(r[14], r[15]);
        *(int4*)o = o0;
        *(int4*)(o + 4) = o1;
        int2 o2;
        o2.x = pk2(r[16], r[17]); o2.y = pk2(r[18], r[19]);
        *(int2*)(o + 8) = o2;
    }
}

// Layer 3 + classifier: gather h2 (40 B in 64 B stride), out fp32
__global__ void agg_l3(const int* __restrict__ P2, const int* __restrict__ bbase,
                       const int* __restrict__ h2,
                       const float* __restrict__ w3l, const float* __restrict__ b3,
                       const float* __restrict__ w3r,
                       const float* __restrict__ wc, const float* __restrict__ bc,
                       float* __restrict__ out) {
    __shared__ float lacc[NPB * 21];  // stride 21, coprime to 32
    __shared__ int ldeg[NPB];
    __shared__ float s_wl[400], s_wr[400], s_b[20], s_wc[160], s_bc[8];
    int t = threadIdx.x, b = blockIdx.x;
    for (int k = t; k < NPB * 21; k += 256) lacc[k] = 0.f;
    ldeg[t] = 0;
    ldeg[t + 256] = 0;
    for (int k = t; k < 400; k += 256) {
        s_wl[k] = w3l[k];
        s_wr[k] = w3r[k];
    }
    if (t < 160) s_wc[t] = wc[t];
    if (t >= 192 && t < 212) s_b[t - 192] = b3[t - 192];
    if (t >= 224 && t < 232) s_bc[t - 224] = bc[t - 224];
    __syncthreads();

    int bb = bbase[b], be = bbase[b + 1];
    int j = bb + t;
    for (; j + 256 < be; j += 512) {  // 2 edges in flight (30 regs of row data)
        int p0 = P2[j], p1 = P2[j + 256];
        const int* r0 = h2 + (long)(p0 & 0x7FFFF) * 16;
        const int* r1 = h2 + (long)(p1 & 0x7FFFF) * 16;
        int4 va0 = *(const int4*)r0, vb0 = *(const int4*)(r0 + 4);
        int2 vc0 = *(const int2*)(r0 + 8);
        int4 va1 = *(const int4*)r1, vb1 = *(const int4*)(r1 + 4);
        int2 vc1 = *(const int2*)(r1 + 8);
        {
            int dl = p0 >> 19;
            float* a = &lacc[dl * 21];
            float2 f;
            f = up2(va0.x); atomicAdd(a + 0, f.x);  atomicAdd(a + 1, f.y);
            f = up2(va0.y); atomicAdd(a + 2, f.x);  atomicAdd(a + 3, f.y);
            f = up2(va0.z); atomicAdd(a + 4, f.x);  atomicAdd(a + 5, f.y);
            f = up2(va0.w); atomicAdd(a + 6, f.x);  atomicAdd(a + 7, f.y);
            f = up2(vb0.x); atomicAdd(a + 8, f.x);  atomicAdd(a + 9, f.y);
            f = up2(vb0.y); atomicAdd(a + 10, f.x); atomicAdd(a + 11, f.y);
            f = up2(vb0.z); atomicAdd(a + 12, f.x); atomicAdd(a + 13, f.y);
            f = up2(vb0.w); atomicAdd(a + 14, f.x); atomicAdd(a + 15, f.y);
            f = up2(vc0.x); atomicAdd(a + 16, f.x); atomicAdd(a + 17, f.y);
            f = up2(vc0.y); atomicAdd(a + 18, f.x); atomicAdd(a + 19, f.y);
            atomicAdd(&ldeg[dl], 1);
        }
        {
            int dl = p1 >> 19;
            float* a = &lacc[dl * 21];
            float2 f;
            f = up2(va1.x); atomicAdd(a + 0, f.x);  atomicAdd(a + 1, f.y);
            f = up2(va1.y); atomicAdd(a + 2, f.x);  atomicAdd(a + 3, f.y);
            f = up2(va1.z); atomicAdd(a + 4, f.x);  atomicAdd(a + 5, f.y);
            f = up2(va1.w); atomicAdd(a + 6, f.x);  atomicAdd(a + 7, f.y);
            f = up2(vb1.x); atomicAdd(a + 8, f.x);  atomicAdd(a + 9, f.y);
            f = up2(vb1.y); atomicAdd(a + 10, f.x); atomicAdd(a + 11, f.y);
            f = up2(vb1.z); atomicAdd(a + 12, f.x); atomicAdd(a + 13, f.y);
            f = up2(vb1.w); atomicAdd(a + 14, f.x); atomicAdd(a + 15, f.y);
            f = up2(vc1.x); atomicAdd(a + 16, f.x); atomicAdd(a + 17, f.y);
            f = up2(vc1.y); atomicAdd(a + 18, f.x); atomicAdd(a + 19, f.y);
            atomicAdd(&ldeg[dl], 1);
        }
    }
    for (; j < be; j += 256) {
        int p = P2[j];
        int dl = p >> 19;
        const int* row = h2 + (long)(p & 0x7FFFF) * 16;
        int4 va = *(const int4*)row, vb = *(const int4*)(row + 4);
        int2 vc = *(const int2*)(row + 8);
        float* a = &lacc[dl * 21];
        float2 f;
        f = up2(va.x); atomicAdd(a + 0, f.x);  atomicAdd(a + 1, f.y);
        f = up2(va.y); atomicAdd(a + 2, f.x);  atomicAdd(a + 3, f.y);
        f = up2(va.z); atomicAdd(a + 4, f.x);  atomicAdd(a + 5, f.y);
        f = up2(va.w); atomicAdd(a + 6, f.x);  atomicAdd(a + 7, f.y);
        f = up2(vb.x); atomicAdd(a + 8, f.x);  atomicAdd(a + 9, f.y);
        f = up2(vb.y); atomicAdd(a + 10, f.x); atomicAdd(a + 11, f.y);
        f = up2(vb.z); atomicAdd(a + 12, f.x); atomicAdd(a + 13, f.y);
        f = up2(vb.w); atomicAdd(a + 14, f.x); atomicAdd(a + 15, f.y);
        f = up2(vc.x); atomicAdd(a + 16, f.x); atomicAdd(a + 17, f.y);
        f = up2(vc.y); atomicAdd(a + 18, f.x); atomicAdd(a + 19, f.y);
        atomicAdd(&ldeg[dl], 1);
    }
    __syncthreads();

    int node0 = b << NPB_LOG;
#pragma unroll
    for (int h = 0; h < 2; ++h) {
        int dl = t + h * 256;
        int node = node0 + dl;
        if (node >= N_NODES) continue;
        float inv = 1.f / fmaxf((float)ldeg[dl], 1.f);
        float a[20];
#pragma unroll
        for (int q = 0; q < 20; ++q) a[q] = lacc[dl * 21 + q] * inv;
        float xv[20];
        {
            const int* row = h2 + (long)node * 16;
            int4 va = *(const int4*)row, vb = *(const int4*)(row + 4);
            int2 vc = *(const int2*)(row + 8);
            float2 f;
            f = up2(va.x); xv[0] = f.x;  xv[1] = f.y;
            f = up2(va.y); xv[2] = f.x;  xv[3] = f.y;
            f = up2(va.z); xv[4] = f.x;  xv[5] = f.y;
            f = up2(va.w); xv[6] = f.x;  xv[7] = f.y;
            f = up2(vb.x); xv[8] = f.x;  xv[9] = f.y;
            f = up2(vb.y); xv[10] = f.x; xv[11] = f.y;
            f = up2(vb.z); xv[12] = f.x; xv[13] = f.y;
            f = up2(vb.w); xv[14] = f.x; xv[15] = f.y;
            f = up2(vc.x); xv[16] = f.x; xv[17] = f.y;
            f = up2(vc.y); xv[18] = f.x; xv[19] = f.y;
        }
        float h3[20];
#pragma unroll
        for (int jj = 0; jj < 20; ++jj) {
            float r = s_b[jj];
#pragma unroll
            for (int kk = 0; kk < 20; ++kk) {
                r += s_wl[jj * 20 + kk] * a[kk] + s_wr[jj * 20 + kk] * xv[kk];
            }
            h3[jj] = fmaxf(r, 0.f);
        }
#pragma unroll
        for (int jj = 0; jj < 8; ++jj) {
            float r = s_bc[jj];
#pragma unroll
            for (int kk = 0; kk < 20; ++kk) {
                r += s_wc[jj * 20 + kk] * h3[kk];
            }
            out[(long)node * 8 + jj] = r;
        }
    }
}

// ============================================================================
// Path B (fallback, small ws): float-atomic version
// ============================================================================

__global__ void deg_kernel(const int* __restrict__ dst, int* __restrict__ deg) {
    int i = blockIdx.x * blockDim.x + threadIdx.x;
    if (i < N_EDGES) atomicAdd(&deg[dst[i]], 1);
}

template <int F>
__global__ void edge_agg(const int* __restrict__ src, const int* __restrict__ dst,
                         const float* __restrict__ h, float* __restrict__ agg) {
    int i = blockIdx.x * blockDim.x + threadIdx.x;
    if (i >= N_EDGES) return;
    int s = src[i];
    int d = dst[i];
    const float* hs = h + (long)s * F;
    float* ad = agg + (long)d * F;
#pragma unroll
    for (int f = 0; f < F; ++f) atomicAdd(&ad[f], hs[f]);
}

template <int FIN, int FOUT>
__global__ void node_apply(const float* __restrict__ agg, const float* __restrict__ hin,
                           const int* __restrict__ deg, const float* __restrict__ wl,
                           const float* __restrict__ bl, const float* __restrict__ wr,
                           float* __restrict__ hout) {
    __shared__ float s_wl[FOUT * FIN];
    __shared__ float s_wr[FOUT * FIN];
    __shared__ float s_b[FOUT];
    for (int t = threadIdx.x; t < FOUT * FIN; t += blockDim.x) {
        s_wl[t] = wl[t];
        s_wr[t] = wr[t];
    }
    for (int t = threadIdx.x; t < FOUT; t += blockDim.x) s_b[t] = bl[t];
    __syncthreads();
    int i = blockIdx.x * blockDim.x + threadIdx.x;
    if (i >= N_NODES) return;
    float inv = 1.0f / fmaxf((float)deg[i], 1.0f);
    float a[FIN], xv[FIN];
#pragma unroll
    for (int kk = 0; kk < FIN; ++kk) {
        a[kk] = agg[(long)i * FIN + kk] * inv;
        xv[kk] = hin[(long)i * FIN + kk];
    }
#pragma unroll
    for (int j = 0; j < FOUT; ++j) {
        float r = s_b[j];
#pragma unroll
        for (int kk = 0; kk < FIN; ++kk) r += s_wl[j * FIN + kk] * a[kk] + s_wr[j * FIN + kk] * xv[kk];
        hout[(long)i * FOUT + j] = fmaxf(r, 0.f);
    }
}

__global__ void node_final_old(const float* __restrict__ agg, const float* __restrict__ hin,
                               const int* __restrict__ deg, const float* __restrict__ w3l,
                               const float* __restrict__ b3, const float* __restrict__ w3r,
                               const float* __restrict__ wc, const float* __restrict__ bc,
                               float* __restrict__ out) {
    __shared__ float s_wl[400];
    __shared__ float s_wr[400];
    __shared__ float s_b[20];
    __shared__ float s_wc[160];
    __shared__ float s_bc[8];
    for (int t = threadIdx.x; t < 400; t += blockDim.x) {
        s_wl[t] = w3l[t];
        s_wr[t] = w3r[t];
    }
    for (int t = threadIdx.x; t < 160; t += blockDim.x) s_wc[t] = wc[t];
    for (int t = threadIdx.x; t < 20; t += blockDim.x) s_b[t] = b3[t];
    for (int t = threadIdx.x; t < 8; t += blockDim.x) s_bc[t] = bc[t];
    __syncthreads();
    int i = blockIdx.x * blockDim.x + threadIdx.x;
    if (i >= N_NODES) return;
    float inv = 1.0f / fmaxf((float)deg[i], 1.0f);
    float a[20], xv[20];
#pragma unroll
    for (int kk = 0; kk < 20; ++kk) {
        a[kk] = agg[(long)i * 20 + kk] * inv;
        xv[kk] = hin[(long)i * 20 + kk];
    }
    float h3[20];
#pragma unroll
    for (int j = 0; j < 20; ++j) {
        float r = s_b[j];
#pragma unroll
        for (int kk = 0; kk < 20; ++kk) r += s_wl[j * 20 + kk] * a[kk] + s_wr[j * 20 + kk] * xv[kk];
        h3[j] = fmaxf(r, 0.f);
    }
#pragma unroll
    for (int j = 0; j < 8; ++j) {
        float r = s_bc[j];
#pragma unroll
        for (int kk = 0; kk < 20; ++kk) r += s_wc[j * 20 + kk] * h3[kk];
        out[(long)i * 8 + j] = r;
    }
}

// ============================================================================

extern "C" void kernel_launch(void* const* d_in, const int* in_sizes, int n_in,
                              void* d_out, int out_size, void* d_ws, size_t ws_size,
                              hipStream_t stream) {
    const float* x = (const float*)d_in[0];
    const int* ei = (const int*)d_in[1];  // [2, E]: src row then dst row
    const float* w1l = (const float*)d_in[2];
    const float* b1 = (const float*)d_in[3];
    const float* w1r = (const float*)d_in[4];
    const float* w2l = (const float*)d_in[5];
    const float* b2 = (const float*)d_in[6];
    const float* w2r = (const float*)d_in[7];
    const float* w3l = (const float*)d_in[8];
    const float* b3 = (const float*)d_in[9];
    const float* w3r = (const float*)d_in[10];
    const float* wc = (const float*)d_in[11];
    const float* bc = (const float*)d_in[12];
    float* out = (float*)d_out;

    const int* src = ei;
    const int* dst = ei + N_EDGES;

    const int BT = 256;
    dim3 blk(BT);
    dim3 egrid((N_EDGES + BT - 1) / BT);
    dim3 ngrid(NB);
    dim3 bgrid(NBUCK);

    // ---- Path A v6 layout (bytes):
    // bbase [0, 4100)            pad to 4224
    // gcur  [4224, 8320)         pad to 8448
    // P     [8448, 64,008,448)   16M ints (dead after tile_sort)
    //   xh  [8448, 4,008,448)        overlay: 500K x 8 B
    //   h1  [4,008,448, 20,008,448)  overlay: 500K x 32 B
    //   h2  [20,008,448, 52,008,448) overlay: 500K x 64 B
    // P2    [64,008,448, 128,008,448) 16M ints, bucket-grouped, tile-sorted
    const size_t NEED_A = 128008448;

    if (ws_size >= NEED_A) {
        char* ws = (char*)d_ws;
        int* bbase = (int*)ws;
        int* gcur = (int*)(ws + 4224);
        int* P = (int*)(ws + 8448);
        int2* xh = (int2*)(ws + 8448);
        int* h1 = (int*)(ws + 4008448);
        int* h2 = (int*)(ws + 20008448);
        int* P2 = (int*)(ws + 64008448);

        hipMemsetAsync(gcur, 0, NBUCK_PAD * sizeof(int), stream);
        bucket_hist<<<1024, blk, 0, stream>>>(dst, gcur);
        bucket_scan<<<1, blk, 0, stream>>>(gcur, bbase);
        bucket_scatter<<<NSB, blk, 0, stream>>>(src, dst, gcur, P);
        tile_sort<<<bgrid, blk, 0, stream>>>(P, bbase, P2);

        convert_x<<<ngrid, blk, 0, stream>>>(x, xh);
        agg_l1<<<bgrid, blk, 0, stream>>>(P2, bbase, xh, x, w1l, b1, w1r, h1);
        agg_l2<<<bgrid, blk, 0, stream>>>(P2, bbase, h1, w2l, b2, w2r, h2);
        agg_l3<<<bgrid, blk, 0, stream>>>(P2, bbase, h2, w3l, b3, w3r, wc, bc, out);
    } else {
        // fallback: float-atomic path (needs 102 MB)
        char* ws = (char*)d_ws;
        int* deg = (int*)ws;
        float* agg = (float*)(ws + 2000000);
        float* h1 = (float*)(ws + 42000000);
        float* h2 = (float*)(ws + 62000000);

        hipMemsetAsync(deg, 0, (size_t)N_NODES * sizeof(int), stream);
        deg_kernel<<<egrid, blk, 0, stream>>>(dst, deg);

        hipMemsetAsync(agg, 0, (size_t)N_NODES * 4 * sizeof(float), stream);
        edge_agg<4><<<egrid, blk, 0, stream>>>(src, dst, x, agg);
        node_apply<4, 10><<<ngrid, blk, 0, stream>>>(agg, x, deg, w1l, b1, w1r, h1);

        hipMemsetAsync(agg, 0, (size_t)N_NODES * 10 * sizeof(float), stream);
        edge_agg<10><<<egrid, blk, 0, stream>>>(src, dst, h1, agg);
        node_apply<10, 20><<<ngrid, blk, 0, stream>>>(agg, h1, deg, w2l, b2, w2r, h2);

        hipMemsetAsync(agg, 0, (size_t)N_NODES * 20 * sizeof(float), stream);
        edge_agg<20><<<egrid, blk, 0, stream>>>(src, dst, h2, agg);
        node_final_old<<<ngrid, blk, 0, stream>>>(agg, h2, deg, w3l, b3, w3r, wc, bc, out);
    }
}